// Round 1
// baseline (1215.221 us; speedup 1.0000x reference)
//
#include <hip/hip_runtime.h>
#include <math.h>

#define CDIM 2048
#define TDIM 2048
#define BDIM 4
#define HDIM 16
#define DDIM 128
#define M1   (BDIM * TDIM)   // 8192
#define N1   (3 * CDIM)      // 6144
#define KK   CDIM            // 2048

typedef unsigned short u16;
typedef __bf16 bf16x8 __attribute__((ext_vector_type(8)));
typedef float f32x4 __attribute__((ext_vector_type(4)));

// ---------- helpers ----------
__device__ __forceinline__ u16 f2b(float f) {
  union { float f; unsigned u; } x; x.f = f;
  unsigned r = x.u + 0x7fffu + ((x.u >> 16) & 1u);
  return (u16)(r >> 16);
}

__device__ __forceinline__ void gload_lds16(const void* g, void* l) {
  __builtin_amdgcn_global_load_lds(
      (__attribute__((address_space(1))) void*)g,
      (__attribute__((address_space(3))) void*)l, 16, 0, 0);
}

// ---------- small prep kernels ----------
__global__ void convert_x(const float* __restrict__ x, u16* __restrict__ xb, int n4) {
  int i = blockIdx.x * blockDim.x + threadIdx.x;
  if (i < n4) {
    float4 v = ((const float4*)x)[i];
    unsigned long long o = (unsigned long long)f2b(v.x)
                         | ((unsigned long long)f2b(v.y) << 16)
                         | ((unsigned long long)f2b(v.z) << 32)
                         | ((unsigned long long)f2b(v.w) << 48);
    ((unsigned long long*)xb)[i] = o;
  }
}

// w [K][N] fp32 -> wt [N][K] bf16
__global__ void transpose_w(const float* __restrict__ w, u16* __restrict__ wt, int K, int N) {
  __shared__ float tile[32][33];
  const int n0 = blockIdx.x * 32, k0 = blockIdx.y * 32;
  const int tx = threadIdx.x & 31, ty = threadIdx.x >> 5;
  for (int r = ty; r < 32; r += 8)
    tile[r][tx] = w[(k0 + r) * N + n0 + tx];
  __syncthreads();
  for (int r = ty; r < 32; r += 8)
    wt[(n0 + r) * K + k0 + tx] = f2b(tile[tx][r]);
}

__global__ void rope_tab(float* __restrict__ cosT, float* __restrict__ sinT) {
  int i = blockIdx.x * blockDim.x + threadIdx.x;   // 0 .. 2048*64-1
  int t = i >> 6, d = i & 63;
  double inv = pow(10000.0, -(double)d / 64.0);
  double a = (double)t * inv;
  cosT[i] = (float)cos(a);
  sinT[i] = (float)sin(a);
}

// v fp32 [bh][t][d] -> vt bf16 [bh][d][t]
__global__ void transpose_v(const float* __restrict__ v, u16* __restrict__ vt) {
  __shared__ float tile[32][33];
  const int bh = blockIdx.z;
  const int t0 = blockIdx.x * 32, d0 = blockIdx.y * 32;
  const int tx = threadIdx.x & 31, ty = threadIdx.x >> 5;
  const float* src = v + (bh * TDIM + t0) * DDIM + d0;
  for (int r = ty; r < 32; r += 8)
    tile[r][tx] = src[r * DDIM + tx];          // tile[t_local][d_local]
  __syncthreads();
  u16* dst = vt + (bh * DDIM + d0) * TDIM + t0;
  for (int r = ty; r < 32; r += 8)
    dst[r * TDIM + tx] = f2b(tile[tx][r]);     // [d_local=r][t_local=tx]
}

// ---------- GEMM1: qkv = x @ w_qkv, epilogue: rope + scatter ----------
__global__ __launch_bounds__(256, 2) void gemm_qkv(
    const u16* __restrict__ A,    // xb [8192][2048]
    const u16* __restrict__ Bt,   // wqkvT [6144][2048]
    const float* __restrict__ cosT, const float* __restrict__ sinT,
    u16* __restrict__ qb, u16* __restrict__ kb,
    float* __restrict__ kout, float* __restrict__ vout)
{
  __shared__ __attribute__((aligned(16))) union {
    struct { u16 A[128 * 32]; u16 B[128 * 32]; } st;   // 16 KB
    float c[64 * 128];                                  // 32 KB
  } sm;
  const int tid = threadIdx.x;
  const int wave = tid >> 6, lane = tid & 63;
  const int quad = lane >> 4, c16 = lane & 15;
  const int m0 = blockIdx.y * 128, n0 = blockIdx.x * 128;
  const int wm = (wave >> 1) * 64, wn = (wave & 1) * 64;

  f32x4 acc[4][4];
  f32x4 zero = {0.f, 0.f, 0.f, 0.f};
#pragma unroll
  for (int i = 0; i < 4; ++i)
#pragma unroll
    for (int j = 0; j < 4; ++j) acc[i][j] = zero;

  const u16* Ab = A + m0 * KK;
  const u16* Bb = Bt + n0 * KK;
  const int rowA = wave * 16 + (lane >> 2);
  const int kof = (lane & 3) * 8;

  for (int k0 = 0; k0 < KK; k0 += 32) {
#pragma unroll
    for (int r = 0; r < 2; ++r) {
      gload_lds16(Ab + (r * 64 + rowA) * KK + k0 + kof, &sm.st.A[(r * 64 + wave * 16) * 32]);
      gload_lds16(Bb + (r * 64 + rowA) * KK + k0 + kof, &sm.st.B[(r * 64 + wave * 16) * 32]);
    }
    __syncthreads();
    bf16x8 af[4], bf_[4];
#pragma unroll
    for (int i = 0; i < 4; ++i) af[i]  = *(const bf16x8*)&sm.st.A[(wm + i * 16 + c16) * 32 + quad * 8];
#pragma unroll
    for (int j = 0; j < 4; ++j) bf_[j] = *(const bf16x8*)&sm.st.B[(wn + j * 16 + c16) * 32 + quad * 8];
#pragma unroll
    for (int i = 0; i < 4; ++i)
#pragma unroll
      for (int j = 0; j < 4; ++j)
        acc[i][j] = __builtin_amdgcn_mfma_f32_16x16x32_bf16(af[i], bf_[j], acc[i][j], 0, 0, 0);
    __syncthreads();
  }

  // epilogue: rope + scatter, two 64-row passes through 32 KB LDS
  const int mat = n0 >> 11;            // 0=q, 1=k, 2=v
  const int h = (n0 & 2047) >> 7;
  for (int pass = 0; pass < 2; ++pass) {
    __syncthreads();
    if ((wave >> 1) == pass) {
#pragma unroll
      for (int i = 0; i < 4; ++i)
#pragma unroll
        for (int j = 0; j < 4; ++j)
#pragma unroll
          for (int r = 0; r < 4; ++r)
            sm.c[(i * 16 + quad * 4 + r) * 128 + wn + j * 16 + c16] = acc[i][j][r];
    }
    __syncthreads();
    for (int it = 0; it < 16; ++it) {
      int p = it * 256 + tid;          // 0..4095
      int lr = p >> 6;                 // local row 0..63
      int d = p & 63;
      float x1 = sm.c[lr * 128 + d];
      float x2 = sm.c[lr * 128 + 64 + d];
      int mg = m0 + pass * 64 + lr;
      int b = mg >> 11, t = mg & 2047;
      int idx = ((b * HDIM + h) * TDIM + t) * DDIM + d;
      if (mat == 2) {
        vout[idx] = x1; vout[idx + 64] = x2;
      } else {
        float cs = cosT[t * 64 + d], sn = sinT[t * 64 + d];
        float o1 = x1 * cs - x2 * sn;
        float o2 = x1 * sn + x2 * cs;
        if (mat == 0) {
          qb[idx] = f2b(o1); qb[idx + 64] = f2b(o2);
        } else {
          kout[idx] = o1; kout[idx + 64] = o2;
          kb[idx] = f2b(o1); kb[idx + 64] = f2b(o2);
        }
      }
    }
  }
}

// ---------- flash attention ----------
__global__ __launch_bounds__(256, 2) void attn(
    const u16* __restrict__ qb, const u16* __restrict__ kb,
    const u16* __restrict__ vt, u16* __restrict__ att)
{
  __shared__ __attribute__((aligned(16))) u16 qs[64 * 128];    // 16 KB
  __shared__ __attribute__((aligned(16))) u16 ks[64 * 128];    // 16 KB
  __shared__ __attribute__((aligned(16))) u16 vts[128 * 64];   // 16 KB
  __shared__ __attribute__((aligned(16))) u16 ps[4][16 * 64];  // 8 KB

  const int tid = threadIdx.x, wave = tid >> 6, lane = tid & 63;
  const int quad = lane >> 4, c16 = lane & 15;
  const int qt = blockIdx.x;   // q tile 0..31
  const int bh = blockIdx.y;   // 0..63
  const int q0 = qt * 64;

  {  // stage q once: 64 rows x 128 d
    const u16* qg = qb + (bh * TDIM + q0) * DDIM;
    int row = wave * 4 + (lane >> 4);
    int dof = (lane & 15) * 8;
#pragma unroll
    for (int r = 0; r < 4; ++r)
      gload_lds16(qg + (r * 16 + row) * DDIM + dof, &qs[(r * 16 + wave * 4) * DDIM]);
  }

  f32x4 o[8];
  f32x4 zero = {0.f, 0.f, 0.f, 0.f};
#pragma unroll
  for (int j = 0; j < 8; ++j) o[j] = zero;
  float mrow[4], lrow[4];
#pragma unroll
  for (int r = 0; r < 4; ++r) { mrow[r] = -INFINITY; lrow[r] = 0.f; }

  const float scale = 0.088388347648318447f;   // 1/sqrt(128)
  const int nchunk = qt + 1;
  for (int kc = 0; kc < nchunk; ++kc) {
    const int kc0 = kc * 64;
    {  // stage k chunk: 64 keys x 128 d
      const u16* kg = kb + (bh * TDIM + kc0) * DDIM;
      int row = wave * 4 + (lane >> 4);
      int dof = (lane & 15) * 8;
#pragma unroll
      for (int r = 0; r < 4; ++r)
        gload_lds16(kg + (r * 16 + row) * DDIM + dof, &ks[(r * 16 + wave * 4) * DDIM]);
    }
    {  // stage v^T chunk: 128 d x 64 keys
      const u16* vg = vt + (bh * DDIM) * TDIM + kc0;
      int row = wave * 8 + (lane >> 3);
      int kof = (lane & 7) * 8;
#pragma unroll
      for (int r = 0; r < 4; ++r)
        gload_lds16(vg + (r * 32 + row) * TDIM + kof, &vts[(r * 32 + wave * 8) * 64]);
    }
    __syncthreads();

    // S = q k^T  (wave's 16 q-rows x 64 keys)
    f32x4 s[4];
#pragma unroll
    for (int j = 0; j < 4; ++j) s[j] = zero;
#pragma unroll
    for (int kstep = 0; kstep < 4; ++kstep) {
      bf16x8 aq = *(const bf16x8*)&qs[(wave * 16 + c16) * DDIM + kstep * 32 + quad * 8];
#pragma unroll
      for (int j = 0; j < 4; ++j) {
        bf16x8 bk = *(const bf16x8*)&ks[(j * 16 + c16) * DDIM + kstep * 32 + quad * 8];
        s[j] = __builtin_amdgcn_mfma_f32_16x16x32_bf16(aq, bk, s[j], 0, 0, 0);
      }
    }

    const bool diag = (kc == qt);
    float mnew[4], alpha[4];
#pragma unroll
    for (int r = 0; r < 4; ++r) {
      float mx = -INFINITY;
#pragma unroll
      for (int j = 0; j < 4; ++j) {
        float sv = s[j][r] * scale;
        if (diag) {
          int key = kc0 + j * 16 + c16;
          int qr = q0 + wave * 16 + quad * 4 + r;
          if (key > qr) sv = -INFINITY;
        }
        s[j][r] = sv;
        mx = fmaxf(mx, sv);
      }
#pragma unroll
      for (int off = 1; off < 16; off <<= 1)
        mx = fmaxf(mx, __shfl_xor(mx, off, 64));
      mnew[r] = fmaxf(mrow[r], mx);
      alpha[r] = __expf(mrow[r] - mnew[r]);
      mrow[r] = mnew[r];
    }
#pragma unroll
    for (int r = 0; r < 4; ++r) {
      float sum = 0.f;
#pragma unroll
      for (int j = 0; j < 4; ++j) {
        float p = __expf(s[j][r] - mnew[r]);
        sum += p;
        ps[wave][(quad * 4 + r) * 64 + j * 16 + c16] = f2b(p);
      }
#pragma unroll
      for (int off = 1; off < 16; off <<= 1)
        sum += __shfl_xor(sum, off, 64);
      lrow[r] = lrow[r] * alpha[r] + sum;
    }
#pragma unroll
    for (int jd = 0; jd < 8; ++jd)
#pragma unroll
      for (int r = 0; r < 4; ++r)
        o[jd][r] *= alpha[r];

    asm volatile("s_waitcnt lgkmcnt(0)" ::: "memory");

    // O += P @ V   (P: 16 x 64 keys, V^T: 128 d x 64 keys)
#pragma unroll
    for (int kstep = 0; kstep < 2; ++kstep) {
      bf16x8 ap = *(const bf16x8*)&ps[wave][c16 * 64 + kstep * 32 + quad * 8];
#pragma unroll
      for (int jd = 0; jd < 8; ++jd) {
        bf16x8 bv = *(const bf16x8*)&vts[(jd * 16 + c16) * 64 + kstep * 32 + quad * 8];
        o[jd] = __builtin_amdgcn_mfma_f32_16x16x32_bf16(ap, bv, o[jd], 0, 0, 0);
      }
    }
    __syncthreads();
  }

  // epilogue: normalize, write att [b*T+t][h*128+d] bf16
  float rinv[4];
#pragma unroll
  for (int r = 0; r < 4; ++r) rinv[r] = 1.f / lrow[r];
  const int b = bh >> 4, h = bh & 15;
#pragma unroll
  for (int jd = 0; jd < 8; ++jd)
#pragma unroll
    for (int r = 0; r < 4; ++r) {
      int t = q0 + wave * 16 + quad * 4 + r;
      int d = jd * 16 + c16;
      att[(b * TDIM + t) * CDIM + h * DDIM + d] = f2b(o[jd][r] * rinv[r]);
    }
}

// ---------- GEMM2: out = att @ w_proj ----------
__global__ __launch_bounds__(256, 2) void gemm_proj(
    const u16* __restrict__ A,    // att [8192][2048]
    const u16* __restrict__ Bt,   // wprojT [2048][2048]
    float* __restrict__ out)
{
  __shared__ __attribute__((aligned(16))) struct { u16 A[128 * 32]; u16 B[128 * 32]; } sm;
  const int tid = threadIdx.x;
  const int wave = tid >> 6, lane = tid & 63;
  const int quad = lane >> 4, c16 = lane & 15;
  const int m0 = blockIdx.y * 128, n0 = blockIdx.x * 128;
  const int wm = (wave >> 1) * 64, wn = (wave & 1) * 64;

  f32x4 acc[4][4];
  f32x4 zero = {0.f, 0.f, 0.f, 0.f};
#pragma unroll
  for (int i = 0; i < 4; ++i)
#pragma unroll
    for (int j = 0; j < 4; ++j) acc[i][j] = zero;

  const u16* Ab = A + m0 * KK;
  const u16* Bb = Bt + n0 * KK;
  const int rowA = wave * 16 + (lane >> 2);
  const int kof = (lane & 3) * 8;

  for (int k0 = 0; k0 < KK; k0 += 32) {
#pragma unroll
    for (int r = 0; r < 2; ++r) {
      gload_lds16(Ab + (r * 64 + rowA) * KK + k0 + kof, &sm.A[(r * 64 + wave * 16) * 32]);
      gload_lds16(Bb + (r * 64 + rowA) * KK + k0 + kof, &sm.B[(r * 64 + wave * 16) * 32]);
    }
    __syncthreads();
    bf16x8 af[4], bf_[4];
#pragma unroll
    for (int i = 0; i < 4; ++i) af[i]  = *(const bf16x8*)&sm.A[(wm + i * 16 + c16) * 32 + quad * 8];
#pragma unroll
    for (int j = 0; j < 4; ++j) bf_[j] = *(const bf16x8*)&sm.B[(wn + j * 16 + c16) * 32 + quad * 8];
#pragma unroll
    for (int i = 0; i < 4; ++i)
#pragma unroll
      for (int j = 0; j < 4; ++j)
        acc[i][j] = __builtin_amdgcn_mfma_f32_16x16x32_bf16(af[i], bf_[j], acc[i][j], 0, 0, 0);
    __syncthreads();
  }

#pragma unroll
  for (int i = 0; i < 4; ++i)
#pragma unroll
    for (int j = 0; j < 4; ++j)
#pragma unroll
      for (int r = 0; r < 4; ++r)
        out[(m0 + wm + i * 16 + quad * 4 + r) * CDIM + n0 + wn + j * 16 + c16] = acc[i][j][r];
}

// ---------- launcher ----------
extern "C" void kernel_launch(void* const* d_in, const int* in_sizes, int n_in,
                              void* d_out, int out_size, void* d_ws, size_t ws_size,
                              hipStream_t stream) {
  (void)in_sizes; (void)n_in; (void)out_size; (void)ws_size;
  const float* x      = (const float*)d_in[0];
  const float* w_qkv  = (const float*)d_in[1];
  const float* w_proj = (const float*)d_in[2];
  float* out  = (float*)d_out;
  float* kout = out + 16777216;
  float* vout = out + 2 * 16777216;

  char* ws = (char*)d_ws;
  u16*   xb     = (u16*)(ws);                   // 33.5 MB (reused as att)
  u16*   wqkvT  = (u16*)(ws + 33554432);        // 25.2 MB
  u16*   wprojT = (u16*)(ws + 58720256);        // 8.4 MB
  float* cosT   = (float*)(ws + 67108864);      // 0.5 MB
  float* sinT   = (float*)(ws + 67633152);      // 0.5 MB
  u16*   qb     = (u16*)(ws + 68157440);        // 33.5 MB
  u16*   kb     = (u16*)(ws + 101711872);       // 33.5 MB
  u16*   vt     = (u16*)(ws + 135266304);       // 33.5 MB  (total ~169 MB)
  u16*   att    = xb;

  convert_x<<<16384, 256, 0, stream>>>(x, xb, 4194304);
  transpose_w<<<dim3(192, 64), 256, 0, stream>>>(w_qkv, wqkvT, KK, N1);
  transpose_w<<<dim3(64, 64), 256, 0, stream>>>(w_proj, wprojT, KK, CDIM);
  rope_tab<<<512, 256, 0, stream>>>(cosT, sinT);
  gemm_qkv<<<dim3(48, 64), 256, 0, stream>>>(xb, wqkvT, cosT, sinT, qb, kb, kout, vout);
  transpose_v<<<dim3(64, 4, 64), 256, 0, stream>>>(vout, vt);
  attn<<<dim3(32, 64), 256, 0, stream>>>(qb, kb, vt, att);
  gemm_proj<<<dim3(16, 64), 256, 0, stream>>>(att, wprojT, out);
}

// Round 3
// 886.947 us; speedup vs baseline: 1.3701x; 1.3701x over previous
//
#include <hip/hip_runtime.h>
#include <math.h>

#define CDIM 2048
#define TDIM 2048
#define BDIM 4
#define HDIM 16
#define DDIM 128
#define M1   (BDIM * TDIM)   // 8192
#define N1   (3 * CDIM)      // 6144
#define KK   CDIM            // 2048

typedef unsigned short u16;
typedef __bf16 bf16x8 __attribute__((ext_vector_type(8)));
typedef float f32x4 __attribute__((ext_vector_type(4)));

// ---------- helpers ----------
__device__ __forceinline__ u16 f2b(float f) {
  union { float f; unsigned u; } x; x.f = f;
  unsigned r = x.u + 0x7fffu + ((x.u >> 16) & 1u);
  return (u16)(r >> 16);
}

__device__ __forceinline__ void gload_lds16(const void* g, void* l) {
  __builtin_amdgcn_global_load_lds(
      (__attribute__((address_space(1))) void*)g,
      (__attribute__((address_space(3))) void*)l, 16, 0, 0);
}

// ---------- small prep kernels ----------
__global__ void convert_x(const float* __restrict__ x, u16* __restrict__ xb, int n4) {
  int i = blockIdx.x * blockDim.x + threadIdx.x;
  if (i < n4) {
    float4 v = ((const float4*)x)[i];
    unsigned long long o = (unsigned long long)f2b(v.x)
                         | ((unsigned long long)f2b(v.y) << 16)
                         | ((unsigned long long)f2b(v.z) << 32)
                         | ((unsigned long long)f2b(v.w) << 48);
    ((unsigned long long*)xb)[i] = o;
  }
}

// w [K][N] fp32 -> wt [N][K] bf16
__global__ void transpose_w(const float* __restrict__ w, u16* __restrict__ wt, int K, int N) {
  __shared__ float tile[32][33];
  const int n0 = blockIdx.x * 32, k0 = blockIdx.y * 32;
  const int tx = threadIdx.x & 31, ty = threadIdx.x >> 5;
  for (int r = ty; r < 32; r += 8)
    tile[r][tx] = w[(k0 + r) * N + n0 + tx];
  __syncthreads();
  for (int r = ty; r < 32; r += 8)
    wt[(n0 + r) * K + k0 + tx] = f2b(tile[tx][r]);
}

__global__ void rope_tab(float* __restrict__ cosT, float* __restrict__ sinT) {
  int i = blockIdx.x * blockDim.x + threadIdx.x;   // 0 .. 2048*64-1
  int t = i >> 6, d = i & 63;
  double inv = pow(10000.0, -(double)d / 64.0);
  double a = (double)t * inv;
  cosT[i] = (float)cos(a);
  sinT[i] = (float)sin(a);
}

// v fp32 [bh][t][d] -> vt bf16 [bh][d][t]
__global__ void transpose_v(const float* __restrict__ v, u16* __restrict__ vt) {
  __shared__ float tile[32][33];
  const int bh = blockIdx.z;
  const int t0 = blockIdx.x * 32, d0 = blockIdx.y * 32;
  const int tx = threadIdx.x & 31, ty = threadIdx.x >> 5;
  const float* src = v + (bh * TDIM + t0) * DDIM + d0;
  for (int r = ty; r < 32; r += 8)
    tile[r][tx] = src[r * DDIM + tx];          // tile[t_local][d_local]
  __syncthreads();
  u16* dst = vt + (bh * DDIM + d0) * TDIM + t0;
  for (int r = ty; r < 32; r += 8)
    dst[r * TDIM + tx] = f2b(tile[tx][r]);     // [d_local=r][t_local=tx]
}

// ---------- GEMM1: qkv = x @ w_qkv, epilogue: rope + scatter ----------
__global__ __launch_bounds__(256, 2) void gemm_qkv(
    const u16* __restrict__ A,    // xb [8192][2048]
    const u16* __restrict__ Bt,   // wqkvT [6144][2048]
    const float* __restrict__ cosT, const float* __restrict__ sinT,
    u16* __restrict__ qb, u16* __restrict__ kb,
    float* __restrict__ kout, float* __restrict__ vout)
{
  __shared__ __attribute__((aligned(16))) union {
    struct { u16 A[128 * 32]; u16 B[128 * 32]; } st;   // 16 KB
    float c[64 * 128];                                  // 32 KB
  } sm;
  const int tid = threadIdx.x;
  const int wave = tid >> 6, lane = tid & 63;
  const int quad = lane >> 4, c16 = lane & 15;
  const int m0 = blockIdx.y * 128, n0 = blockIdx.x * 128;
  const int wm = (wave >> 1) * 64, wn = (wave & 1) * 64;

  f32x4 acc[4][4];
  f32x4 zero = {0.f, 0.f, 0.f, 0.f};
#pragma unroll
  for (int i = 0; i < 4; ++i)
#pragma unroll
    for (int j = 0; j < 4; ++j) acc[i][j] = zero;

  const u16* Ab = A + m0 * KK;
  const u16* Bb = Bt + n0 * KK;
  const int rowA = wave * 16 + (lane >> 2);
  const int kof = (lane & 3) * 8;

  for (int k0 = 0; k0 < KK; k0 += 32) {
#pragma unroll
    for (int r = 0; r < 2; ++r) {
      gload_lds16(Ab + (r * 64 + rowA) * KK + k0 + kof, &sm.st.A[(r * 64 + wave * 16) * 32]);
      gload_lds16(Bb + (r * 64 + rowA) * KK + k0 + kof, &sm.st.B[(r * 64 + wave * 16) * 32]);
    }
    __syncthreads();
    bf16x8 af[4], bf_[4];
#pragma unroll
    for (int i = 0; i < 4; ++i) af[i]  = *(const bf16x8*)&sm.st.A[(wm + i * 16 + c16) * 32 + quad * 8];
#pragma unroll
    for (int j = 0; j < 4; ++j) bf_[j] = *(const bf16x8*)&sm.st.B[(wn + j * 16 + c16) * 32 + quad * 8];
#pragma unroll
    for (int i = 0; i < 4; ++i)
#pragma unroll
      for (int j = 0; j < 4; ++j)
        acc[i][j] = __builtin_amdgcn_mfma_f32_16x16x32_bf16(af[i], bf_[j], acc[i][j], 0, 0, 0);
    __syncthreads();
  }

  // epilogue: rope + scatter, two 64-row passes through 32 KB LDS
  const int mat = n0 >> 11;            // 0=q, 1=k, 2=v
  const int h = (n0 & 2047) >> 7;
  const float qscale = 0.088388347648318447f;   // 1/sqrt(128) folded into q
  for (int pass = 0; pass < 2; ++pass) {
    __syncthreads();
    if ((wave >> 1) == pass) {
#pragma unroll
      for (int i = 0; i < 4; ++i)
#pragma unroll
        for (int j = 0; j < 4; ++j)
#pragma unroll
          for (int r = 0; r < 4; ++r)
            sm.c[(i * 16 + quad * 4 + r) * 128 + wn + j * 16 + c16] = acc[i][j][r];
    }
    __syncthreads();
    for (int it = 0; it < 16; ++it) {
      int p = it * 256 + tid;          // 0..4095
      int lr = p >> 6;                 // local row 0..63
      int d = p & 63;
      float x1 = sm.c[lr * 128 + d];
      float x2 = sm.c[lr * 128 + 64 + d];
      int mg = m0 + pass * 64 + lr;
      int b = mg >> 11, t = mg & 2047;
      int idx = ((b * HDIM + h) * TDIM + t) * DDIM + d;
      if (mat == 2) {
        vout[idx] = x1; vout[idx + 64] = x2;
      } else {
        float cs = cosT[t * 64 + d], sn = sinT[t * 64 + d];
        float o1 = x1 * cs - x2 * sn;
        float o2 = x1 * sn + x2 * cs;
        if (mat == 0) {
          qb[idx] = f2b(o1 * qscale); qb[idx + 64] = f2b(o2 * qscale);
        } else {
          kout[idx] = o1; kout[idx + 64] = o2;
          kb[idx] = f2b(o1); kb[idx + 64] = f2b(o2);
        }
      }
    }
  }
}

// ---------- flash attention: 128 q-rows/block, swizzled LDS, Q in regs ----------
__global__ __launch_bounds__(256, 2) void attn(
    const u16* __restrict__ qb, const u16* __restrict__ kb,
    const u16* __restrict__ vt, u16* __restrict__ att)
{
  __shared__ __attribute__((aligned(16))) u16 sh[24576];  // 48 KB
  u16* const ksm = sh;                // [0,8192)     64 keys x 128 d (swizzled)
  u16* const vsm = sh + 8192;         // [8192,16384) 128 d x 64 keys (swizzled)
  u16* const psm = sh + 16384;        // [16384,24576) per-wave 2048: [g][16 q][64 keys] (swizzled)

  const int tid = threadIdx.x, wave = tid >> 6, lane = tid & 63;
  const int quad = lane >> 4, c16 = lane & 15;
  const int qt = blockIdx.x;          // 0..15
  const int bh = blockIdx.y;          // 0..63
  const int q0 = qt * 128;

  // ---- stage Q (128x128) into sh[0..32KB), extract frags to regs ----
  {
    const u16* qg = qb + (bh * TDIM + q0) * DDIM;
    const int rowl = wave * 4 + (lane >> 4);
    const int ch = lane & 15;
#pragma unroll
    for (int r = 0; r < 8; ++r) {
      int row = r * 16 + rowl;
      gload_lds16(qg + row * DDIM + (ch ^ (row & 15)) * 8,
                  &sh[(r * 16 + wave * 4) * 128]);
    }
  }
  __syncthreads();
  bf16x8 qf[2][4];
#pragma unroll
  for (int g = 0; g < 2; ++g)
#pragma unroll
    for (int kp = 0; kp < 4; ++kp)
      qf[g][kp] = *(const bf16x8*)&sh[(g * 64 + wave * 16 + c16) * 128 +
                                      (((kp * 4 + quad) ^ c16) * 8)];
  __syncthreads();   // sh reusable for K/V now

  f32x4 o[2][8];
  f32x4 zero = {0.f, 0.f, 0.f, 0.f};
#pragma unroll
  for (int g = 0; g < 2; ++g)
#pragma unroll
    for (int jd = 0; jd < 8; ++jd) o[g][jd] = zero;
  float mrow[2][4], lrow[2][4];
#pragma unroll
  for (int g = 0; g < 2; ++g)
#pragma unroll
    for (int r = 0; r < 4; ++r) { mrow[g][r] = -INFINITY; lrow[g][r] = 0.f; }

  const int nchunk = 2 * qt + 2;
  for (int kc = 0; kc < nchunk; ++kc) {
    const int kc0 = kc * 64;
    {  // stage K (64x128) and V^T (128x64), swizzled
      const u16* kg = kb + (bh * TDIM + kc0) * DDIM;
      const int rowl = wave * 4 + (lane >> 4);
      const int ch = lane & 15;
#pragma unroll
      for (int r = 0; r < 4; ++r) {
        int row = r * 16 + rowl;
        gload_lds16(kg + row * DDIM + (ch ^ (row & 15)) * 8,
                    &ksm[(r * 16 + wave * 4) * 128]);
      }
      const u16* vg = vt + bh * (DDIM * TDIM) + kc0;
      const int rowv = wave * 8 + (lane >> 3);
      const int chv = lane & 7;
#pragma unroll
      for (int r = 0; r < 4; ++r) {
        int row = r * 32 + rowv;
        gload_lds16(vg + row * TDIM + (chv ^ (row & 7)) * 8,
                    &vsm[(r * 32 + wave * 8) * 64]);
      }
    }
    __syncthreads();

    // S = Q K^T for both q-groups (scale pre-folded into Q)
    f32x4 st[2][4];
#pragma unroll
    for (int g = 0; g < 2; ++g)
#pragma unroll
      for (int j = 0; j < 4; ++j) st[g][j] = zero;
#pragma unroll
    for (int kp = 0; kp < 4; ++kp) {
#pragma unroll
      for (int j = 0; j < 4; ++j) {
        bf16x8 bk = *(const bf16x8*)&ksm[(j * 16 + c16) * 128 +
                                         (((kp * 4 + quad) ^ c16) * 8)];
        st[0][j] = __builtin_amdgcn_mfma_f32_16x16x32_bf16(qf[0][kp], bk, st[0][j], 0, 0, 0);
        st[1][j] = __builtin_amdgcn_mfma_f32_16x16x32_bf16(qf[1][kp], bk, st[1][j], 0, 0, 0);
      }
    }

    // online softmax + P write (swizzled, conflict-free)
    u16* const pw = psm + wave * 2048;
    float al2[2][4];
#pragma unroll
    for (int g = 0; g < 2; ++g) {
      // mask needed on the group's diagonal chunk AND any chunk beyond it
      // (for g=0, chunk kc==2qt+1 is entirely future keys -> fully masked)
      const bool dg = (kc >= 2 * qt + g);
      const int qrow_base = q0 + g * 64 + wave * 16 + quad * 4;
#pragma unroll
      for (int r = 0; r < 4; ++r) {
        float mx = -INFINITY;
#pragma unroll
        for (int j = 0; j < 4; ++j) {
          float sv = st[g][j][r];
          if (dg && (kc0 + j * 16 + c16 > qrow_base + r)) sv = -INFINITY;
          st[g][j][r] = sv;
          mx = fmaxf(mx, sv);
        }
        mx = fmaxf(mx, __shfl_xor(mx, 1, 64));
        mx = fmaxf(mx, __shfl_xor(mx, 2, 64));
        mx = fmaxf(mx, __shfl_xor(mx, 4, 64));
        mx = fmaxf(mx, __shfl_xor(mx, 8, 64));
        float mnew = fmaxf(mrow[g][r], mx);
        float al = __expf(mrow[g][r] - mnew);
        mrow[g][r] = mnew;
        al2[g][r] = al;
        float sum = 0.f;
        const int row16 = quad * 4 + r;
#pragma unroll
        for (int j = 0; j < 4; ++j) {
          float p = __expf(st[g][j][r] - mnew);
          sum += p;
          int chunk = (j * 2 + (c16 >> 3)) ^ (row16 & 7);
          pw[g * 1024 + row16 * 64 + chunk * 8 + (c16 & 7)] = f2b(p);
        }
        sum += __shfl_xor(sum, 1, 64);
        sum += __shfl_xor(sum, 2, 64);
        sum += __shfl_xor(sum, 4, 64);
        sum += __shfl_xor(sum, 8, 64);
        lrow[g][r] = lrow[g][r] * al + sum;
      }
#pragma unroll
      for (int jd = 0; jd < 8; ++jd)
#pragma unroll
        for (int r = 0; r < 4; ++r)
          o[g][jd][r] *= al2[g][r];
    }

    asm volatile("s_waitcnt lgkmcnt(0)" ::: "memory");

    // O += P V
#pragma unroll
    for (int s = 0; s < 2; ++s) {
      const int chp = ((s * 4 + quad) ^ (c16 & 7)) * 8;
      bf16x8 ap0 = *(const bf16x8*)&pw[c16 * 64 + chp];
      bf16x8 ap1 = *(const bf16x8*)&pw[1024 + c16 * 64 + chp];
#pragma unroll
      for (int jd = 0; jd < 8; ++jd) {
        bf16x8 bv = *(const bf16x8*)&vsm[(jd * 16 + c16) * 64 + chp];
        o[0][jd] = __builtin_amdgcn_mfma_f32_16x16x32_bf16(ap0, bv, o[0][jd], 0, 0, 0);
        o[1][jd] = __builtin_amdgcn_mfma_f32_16x16x32_bf16(ap1, bv, o[1][jd], 0, 0, 0);
      }
    }
    __syncthreads();
  }

  // epilogue: normalize, write att [b*T+t][h*128+d] bf16
  const int b = bh >> 4, h = bh & 15;
#pragma unroll
  for (int g = 0; g < 2; ++g) {
    float ri[4];
#pragma unroll
    for (int r = 0; r < 4; ++r) ri[r] = 1.f / lrow[g][r];
#pragma unroll
    for (int jd = 0; jd < 8; ++jd)
#pragma unroll
      for (int r = 0; r < 4; ++r) {
        int t = q0 + g * 64 + wave * 16 + quad * 4 + r;
        att[(b * TDIM + t) * CDIM + h * DDIM + jd * 16 + c16] = f2b(o[g][jd][r] * ri[r]);
      }
  }
}

// ---------- GEMM2: out = att @ w_proj ----------
__global__ __launch_bounds__(256, 2) void gemm_proj(
    const u16* __restrict__ A,    // att [8192][2048]
    const u16* __restrict__ Bt,   // wprojT [2048][2048]
    float* __restrict__ out)
{
  __shared__ __attribute__((aligned(16))) struct { u16 A[128 * 32]; u16 B[128 * 32]; } sm;
  const int tid = threadIdx.x;
  const int wave = tid >> 6, lane = tid & 63;
  const int quad = lane >> 4, c16 = lane & 15;
  const int m0 = blockIdx.y * 128, n0 = blockIdx.x * 128;
  const int wm = (wave >> 1) * 64, wn = (wave & 1) * 64;

  f32x4 acc[4][4];
  f32x4 zero = {0.f, 0.f, 0.f, 0.f};
#pragma unroll
  for (int i = 0; i < 4; ++i)
#pragma unroll
    for (int j = 0; j < 4; ++j) acc[i][j] = zero;

  const u16* Ab = A + m0 * KK;
  const u16* Bb = Bt + n0 * KK;
  const int rowA = wave * 16 + (lane >> 2);
  const int kof = (lane & 3) * 8;

  for (int k0 = 0; k0 < KK; k0 += 32) {
#pragma unroll
    for (int r = 0; r < 2; ++r) {
      gload_lds16(Ab + (r * 64 + rowA) * KK + k0 + kof, &sm.A[(r * 64 + wave * 16) * 32]);
      gload_lds16(Bb + (r * 64 + rowA) * KK + k0 + kof, &sm.B[(r * 64 + wave * 16) * 32]);
    }
    __syncthreads();
    bf16x8 af[4], bf_[4];
#pragma unroll
    for (int i = 0; i < 4; ++i) af[i]  = *(const bf16x8*)&sm.A[(wm + i * 16 + c16) * 32 + quad * 8];
#pragma unroll
    for (int j = 0; j < 4; ++j) bf_[j] = *(const bf16x8*)&sm.B[(wn + j * 16 + c16) * 32 + quad * 8];
#pragma unroll
    for (int i = 0; i < 4; ++i)
#pragma unroll
      for (int j = 0; j < 4; ++j)
        acc[i][j] = __builtin_amdgcn_mfma_f32_16x16x32_bf16(af[i], bf_[j], acc[i][j], 0, 0, 0);
    __syncthreads();
  }

#pragma unroll
  for (int i = 0; i < 4; ++i)
#pragma unroll
    for (int j = 0; j < 4; ++j)
#pragma unroll
      for (int r = 0; r < 4; ++r)
        out[(m0 + wm + i * 16 + quad * 4 + r) * CDIM + n0 + wn + j * 16 + c16] = acc[i][j][r];
}

// ---------- launcher ----------
extern "C" void kernel_launch(void* const* d_in, const int* in_sizes, int n_in,
                              void* d_out, int out_size, void* d_ws, size_t ws_size,
                              hipStream_t stream) {
  (void)in_sizes; (void)n_in; (void)out_size; (void)ws_size;
  const float* x      = (const float*)d_in[0];
  const float* w_qkv  = (const float*)d_in[1];
  const float* w_proj = (const float*)d_in[2];
  float* out  = (float*)d_out;
  float* kout = out + 16777216;
  float* vout = out + 2 * 16777216;

  char* ws = (char*)d_ws;
  u16*   xb     = (u16*)(ws);                   // 33.5 MB (reused as att)
  u16*   wqkvT  = (u16*)(ws + 33554432);        // 25.2 MB
  u16*   wprojT = (u16*)(ws + 58720256);        // 8.4 MB
  float* cosT   = (float*)(ws + 67108864);      // 0.5 MB
  float* sinT   = (float*)(ws + 67633152);      // 0.5 MB
  u16*   qb     = (u16*)(ws + 68157440);        // 33.5 MB
  u16*   kb     = (u16*)(ws + 101711872);       // 33.5 MB
  u16*   vt     = (u16*)(ws + 135266304);       // 33.5 MB  (total ~169 MB)
  u16*   att    = xb;

  convert_x<<<16384, 256, 0, stream>>>(x, xb, 4194304);
  transpose_w<<<dim3(192, 64), 256, 0, stream>>>(w_qkv, wqkvT, KK, N1);
  transpose_w<<<dim3(64, 64), 256, 0, stream>>>(w_proj, wprojT, KK, CDIM);
  rope_tab<<<512, 256, 0, stream>>>(cosT, sinT);
  gemm_qkv<<<dim3(48, 64), 256, 0, stream>>>(xb, wqkvT, cosT, sinT, qb, kb, kout, vout);
  transpose_v<<<dim3(64, 4, 64), 256, 0, stream>>>(vout, vt);
  attn<<<dim3(16, 64), 256, 0, stream>>>(qb, kb, vt, att);
  gemm_proj<<<dim3(16, 64), 256, 0, stream>>>(att, wprojT, out);
}